// Round 4
// baseline (2088.088 us; speedup 1.0000x reference)
//
#include <hip/hip_runtime.h>
#include <math.h>

// ---------------- constants ----------------
#define MS 128
#define MV 64
#define RBF 32
#define HID 32
#define TPW 384           // MS+MS+MV+MV
#define OS 256
#define OV 128
#define EB 8

__device__ __forceinline__ float sspf(float x) {
    // softplus(x) - log(2), numerically stable
    float r = (x > 0.0f) ? (x + log1pf(expf(-x))) : log1pf(expf(x));
    return r - 0.6931471805599453f;
}
__device__ __forceinline__ float siluf(float x) {
    return x / (1.0f + expf(-x));
}

__constant__ float INV_S128 = 0.08838834764831845f;
__constant__ float INV_S64  = 0.125f;
__constant__ float INV_S320 = 0.05590169943749474f;
__constant__ float INV_S32  = 0.17677669529663687f;
__constant__ float INV_S192 = 0.07216878364870323f;
#define C1F 0.8660254037844386f
#define INV_S3F 0.5773502691896258f

// ---------------- sort pipeline ----------------
__global__ void k_zeroi(int* __restrict__ p, int n) {
    int i = blockIdx.x * blockDim.x + threadIdx.x;
    int stride = gridDim.x * blockDim.x;
    for (; i < n; i += stride) p[i] = 0;
}

__global__ void k_hist(const int* __restrict__ ei, int* __restrict__ deg, int nEdges) {
    int e = blockIdx.x * blockDim.x + threadIdx.x;
    int stride = gridDim.x * blockDim.x;
    for (; e < nEdges; e += stride) atomicAdd(&deg[ei[e]], 1);
}

// single-block exclusive scan over deg[0..n) -> rowStart[0..n]
__global__ __launch_bounds__(1024) void k_scan(const int* __restrict__ deg,
                                               int* __restrict__ rowStart, int n) {
    __shared__ int s[1024];
    const int t = threadIdx.x;
    const int CH = (n + 1023) >> 10;
    const int beg = t * CH, end = min(beg + CH, n);
    int sum = 0;
    for (int i = beg; i < end; ++i) sum += deg[i];
    s[t] = sum;
    __syncthreads();
    for (int off = 1; off < 1024; off <<= 1) {
        int v = (t >= off) ? s[t - off] : 0;
        __syncthreads();
        s[t] += v;
        __syncthreads();
    }
    int run = s[t] - sum;   // exclusive prefix of this thread's chunk
    for (int i = beg; i < end; ++i) { rowStart[i] = run; run += deg[i]; }
    if (t == 1023) rowStart[n] = s[1023];
}

__global__ void k_perm(const int* __restrict__ ei, const int* __restrict__ rowStart,
                       int* __restrict__ cursor, int* __restrict__ perm, int nEdges) {
    int e = blockIdx.x * blockDim.x + threadIdx.x;
    int stride = gridDim.x * blockDim.x;
    for (; e < nEdges; e += stride) {
        int d = ei[e];
        int pos = rowStart[d] + atomicAdd(&cursor[d], 1);
        perm[pos] = e;
    }
}

// ---------------- K0: fold Wl1 rows 0..127 + 128..255 ----------------
__global__ void k_prep(const float* __restrict__ Wl1, float* __restrict__ Wl1p) {
    int i = blockIdx.x * blockDim.x + threadIdx.x;
    if (i < 128 * 32) Wl1p[i] = Wl1[i] + Wl1[128 * 32 + i];
}

// ---------------- K1: node kernel (unchanged) ----------------
__global__ __launch_bounds__(192) void k_node(
    const float* __restrict__ x,
    const float* __restrict__ Wpre_s, const float* __restrict__ bpre_s,
    const float* __restrict__ Wpre_v,
    const float* __restrict__ Wg1, const float* __restrict__ bg1,
    const float* __restrict__ Wg2, const float* __restrict__ bg2,
    const float* __restrict__ Wn_s, const float* __restrict__ bn_s,
    const float* __restrict__ Wn_v,
    const float* __restrict__ Wl1p,
    float* __restrict__ preV, float* __restrict__ qv,
    float* __restrict__ xs3, float* __restrict__ xv3,
    int nNodes)
{
    __shared__ float sF0[16 * 192];  // xs | vnorm  (f0); later xv2
    __shared__ float sXV[16 * 192];  // xv
    __shared__ float sA[16 * 192];   // pre_s, then h1
    __shared__ float sB[16 * 192];   // g

    const int t = threadIdx.x;
    const int n0 = blockIdx.x * 16;

    for (int idx = t; idx < 16 * 320; idx += 192) {
        int i = idx / 320, j = idx - i * 320;
        int n = n0 + i;
        float v = (n < nNodes) ? x[(size_t)n * 320 + j] : 0.0f;
        if (j < 128) sF0[i * 192 + j] = v;
        else         sXV[i * 192 + (j - 128)] = v;
    }
    __syncthreads();

    for (int task = t; task < 16 * 64; task += 192) {
        int i = task >> 6, u = task & 63;
        float a = sXV[i * 192 + u * 3];
        float b = sXV[i * 192 + u * 3 + 1];
        float c = sXV[i * 192 + u * 3 + 2];
        sF0[i * 192 + 128 + u] = sqrtf(a * a + b * b + c * c + 1e-12f);
    }

    {
        int c = t >> 6, o = t & 63;
        float acc[16];
#pragma unroll
        for (int i = 0; i < 16; ++i) acc[i] = 0.0f;
        for (int u = 0; u < 64; ++u) {
            float w = Wpre_v[u * 64 + o];
#pragma unroll
            for (int i = 0; i < 16; ++i) acc[i] += sXV[i * 192 + u * 3 + c] * w;
        }
#pragma unroll
        for (int i = 0; i < 16; ++i) {
            int n = n0 + i;
            if (n < nNodes) preV[(size_t)n * 192 + o * 3 + c] = acc[i] * INV_S64;
        }
    }
    __syncthreads();

    if (t < 128) {
        float acc[16];
#pragma unroll
        for (int i = 0; i < 16; ++i) acc[i] = 0.0f;
        for (int u = 0; u < 128; ++u) {
            float w = Wpre_s[u * 128 + t];
#pragma unroll
            for (int i = 0; i < 16; ++i) acc[i] += sF0[i * 192 + u] * w;
        }
        float b = bpre_s[t];
#pragma unroll
        for (int i = 0; i < 16; ++i) sA[i * 192 + t] = acc[i] * INV_S128 + b;
    }
    __syncthreads();

    for (int task = t; task < 16 * 32; task += 192) {
        int i = task >> 5, o = task & 31;
        float a = 0.0f;
        for (int u = 0; u < 128; ++u) a += sA[i * 192 + u] * Wl1p[u * 32 + o];
        int n = n0 + i;
        if (n < nNodes) qv[(size_t)n * 32 + o] = a;
    }
    __syncthreads();

    {
        float acc[16];
#pragma unroll
        for (int i = 0; i < 16; ++i) acc[i] = 0.0f;
        for (int u = 0; u < 192; ++u) {
            float w = Wg1[u * 192 + t];
#pragma unroll
            for (int i = 0; i < 16; ++i) acc[i] += sF0[i * 192 + u] * w;
        }
        float b = bg1[t];
        __syncthreads();
#pragma unroll
        for (int i = 0; i < 16; ++i) sA[i * 192 + t] = siluf(acc[i] + b);
    }
    __syncthreads();

    {
        float acc[16];
#pragma unroll
        for (int i = 0; i < 16; ++i) acc[i] = 0.0f;
        for (int u = 0; u < 192; ++u) {
            float w = Wg2[u * 192 + t];
#pragma unroll
            for (int i = 0; i < 16; ++i) acc[i] += sA[i * 192 + u] * w;
        }
        float b = bg2[t];
#pragma unroll
        for (int i = 0; i < 16; ++i) sB[i * 192 + t] = acc[i] + b;
    }
    __syncthreads();

    if (t < 128) {
        float acc[16];
#pragma unroll
        for (int i = 0; i < 16; ++i) acc[i] = 0.0f;
        for (int u = 0; u < 128; ++u) {
            float w = Wn_s[u * 128 + t];
#pragma unroll
            for (int i = 0; i < 16; ++i) acc[i] += sB[i * 192 + u] * w;
        }
        float b = bn_s[t];
#pragma unroll
        for (int i = 0; i < 16; ++i) {
            int n = n0 + i;
            if (n < nNodes) xs3[(size_t)n * 128 + t] = acc[i] * INV_S128 + b;
        }
    }

    {
        int u = t / 3;
#pragma unroll
        for (int i = 0; i < 16; ++i) {
            sF0[i * 192 + t] = sXV[i * 192 + t] * sB[i * 192 + 128 + u];
        }
    }
    __syncthreads();

    {
        int c = t >> 6, o = t & 63;
        float acc[16];
#pragma unroll
        for (int i = 0; i < 16; ++i) acc[i] = 0.0f;
        for (int u = 0; u < 64; ++u) {
            float w = Wn_v[u * 64 + o];
#pragma unroll
            for (int i = 0; i < 16; ++i) acc[i] += sF0[i * 192 + u * 3 + c] * w;
        }
#pragma unroll
        for (int i = 0; i < 16; ++i) {
            int n = n0 + i;
            if (n < nNodes) xv3[(size_t)n * 192 + o * 3 + c] = acc[i] * INV_S64;
        }
    }
}

// ---------------- K2: dst-sorted edge kernel, one block per node ----------------
__global__ __launch_bounds__(384) void k_edge2(
    const int* __restrict__ ei,
    const float* __restrict__ ea,
    const float* __restrict__ esh,
    const float* __restrict__ Wf1, const float* __restrict__ Wf2,
    const float* __restrict__ Wl1, const float* __restrict__ Wl2,
    const float* __restrict__ preV, const float* __restrict__ qv,
    const float* __restrict__ xs3, const float* __restrict__ xv3,
    const int* __restrict__ rowStart, const int* __restrict__ perm,
    float* __restrict__ acc,
    int nEdges)
{
    __shared__ float sWf1[32 * 32];
    __shared__ float sWl1c[64 * 32];
    __shared__ float sQ[32];          // qv[n]
    __shared__ float sPd[192];        // preV[n]
    __shared__ float sAcc[768];       // per-node accumulator (thread t owns t, t+384)
    __shared__ float sEA[EB * 32];
    __shared__ float sSH[EB * 4];
    __shared__ float sIp1[EB * 64];
    __shared__ float sH[EB * 64];     // [e*64+0..31]=hA, [e*64+32..63]=hB
    __shared__ float sW[EB * 384];
    __shared__ int sSrc[EB];

    const int t = threadIdx.x;
    const int n = blockIdx.x;

    // persistent per-thread weight columns
    float rWf2[32], rWl2[32];
#pragma unroll
    for (int u = 0; u < 32; ++u) {
        rWf2[u] = Wf2[u * 384 + t];
        rWl2[u] = Wl2[u * 384 + t];
    }
    for (int i = t; i < 32 * 32; i += 384) sWf1[i] = Wf1[i];
    for (int i = t; i < 64 * 32; i += 384) sWl1c[i] = Wl1[256 * 32 + i];
    if (t < 32) sQ[t] = qv[(size_t)n * 32 + t];
    if (t >= 64 && t < 256) sPd[t - 64] = preV[(size_t)n * 192 + (t - 64)];
    sAcc[t] = 0.0f;
    sAcc[t + 384] = 0.0f;

    const int e_beg = rowStart[n];
    const int e_end = rowStart[n + 1];

    for (int base = e_beg; base < e_end; base += EB) {
        const int rem = min(EB, e_end - base);
        __syncthreads();   // staging buffers reused; also covers prologue writes

        // ---- stage per-edge data via perm ----
        if (t < 256) {
            int e = t >> 5, o = t & 31;
            float v = 0.0f;
            if (e < rem) { int ed = perm[base + e]; v = ea[(size_t)ed * 32 + o]; }
            sEA[t] = v;
        } else if (t < 288) {
            int k = t - 256, e = k >> 2, c = k & 3;
            float v = 0.0f;
            if (e < rem) { int ed = perm[base + e]; v = esh[(size_t)ed * 4 + c]; }
            sSH[k] = v;
        } else if (t < 296) {
            int e = t - 288;
            sSrc[e] = (e < rem) ? ei[nEdges + perm[base + e]] : n;  // dummy = self
        }
        __syncthreads();

        // ---- ip1 (preV[dst] from LDS) ----
        for (int task = t; task < EB * 64; task += 384) {
            int e = task >> 6, u = task & 63;
            const float* ps = preV + (size_t)sSrc[e] * 192 + u * 3;
            float a = sPd[u * 3] * ps[0] + sPd[u * 3 + 1] * ps[1] + sPd[u * 3 + 2] * ps[2];
            sIp1[task] = a * (1.0f / 3.0f);
        }
        __syncthreads();

        // ---- hA / hB ----
        if (t < 256) {
            int e = t >> 5, o = t & 31;
            float a = sQ[o];
#pragma unroll 8
            for (int u = 0; u < 64; ++u) a += sIp1[e * 64 + u] * sWl1c[u * 32 + o];
            sH[e * 64 + 32 + o] = sspf(a * INV_S320);
        } else {
#pragma unroll
            for (int k = 0; k < 2; ++k) {
                int task = (t - 256) + 128 * k;
                int e = task >> 5, o = task & 31;
                float a = 0.0f;
#pragma unroll 8
                for (int u = 0; u < 32; ++u) a += sEA[e * 32 + u] * sWf1[u * 32 + o];
                sH[e * 64 + o] = sspf(a * INV_S32);
            }
        }
        __syncthreads();

        // ---- w = (hA@Wf2) * (hB@Wl2) / 32 ----
        for (int e = 0; e < EB; ++e) {
            float a = 0.0f, b = 0.0f;
#pragma unroll
            for (int u = 0; u < 32; ++u) {
                a += sH[e * 64 + u] * rWf2[u];
                b += sH[e * 64 + 32 + u] * rWl2[u];
            }
            sW[e * 384 + t] = a * b * (1.0f / 32.0f);
        }
        __syncthreads();

        // ---- tensor products, accumulate into LDS (race-free: thread owns t, t+384) ----
        for (int e = 0; e < rem; ++e) {
            int s = sSrc[e];
            float sh0 = sSH[e * 4 + 0];
            float sh1a = sSH[e * 4 + 1], sh1b = sSH[e * 4 + 2], sh1c = sSH[e * 4 + 3];
#pragma unroll
            for (int half = 0; half < 2; ++half) {
                int p = t + half * 384;
                float val;
                if (p < 128) {
                    val = 0.5f * sW[e * 384 + p] * xs3[(size_t)s * 128 + p] * sh0;
                } else if (p < 192) {
                    int j = p - 128;
                    const float* hv = xv3 + (size_t)s * 192 + j * 3;
                    float dot = hv[0] * sh1a + hv[1] * sh1b + hv[2] * sh1c;
                    val = 0.5f * sW[e * 384 + 320 + j] * dot * INV_S3F;
                } else {
                    int q2 = p - 192;
                    int m = q2 / 3, c = q2 - m * 3;
                    float shc = sSH[e * 4 + 1 + c];
                    if (m < 128) {
                        val = C1F * sW[e * 384 + 128 + m] * xs3[(size_t)s * 128 + m] * shc;
                    } else {
                        int j = m - 128;
                        val = C1F * sW[e * 384 + 256 + j] * xv3[(size_t)s * 192 + j * 3 + c] * sh0;
                    }
                }
                sAcc[p] += val;
            }
        }
    }

    // ---- write node row once (no atomics) ----
    acc[(size_t)n * 768 + t]       = sAcc[t];
    acc[(size_t)n * 768 + 384 + t] = sAcc[t + 384];
}

// ---------------- K3: output kernel (unchanged) ----------------
__global__ __launch_bounds__(384) void k_out(
    const float* __restrict__ acc,
    const float* __restrict__ Wo_s, const float* __restrict__ bo_s,
    const float* __restrict__ Wo_v,
    float* __restrict__ out, int nNodes)
{
    __shared__ float sAcc[16 * 768];
    const int t = threadIdx.x;
    const int n0 = blockIdx.x * 16;

    for (int idx = t; idx < 16 * 768; idx += 384) {
        int i = idx / 768;
        int n = n0 + i;
        sAcc[idx] = (n < nNodes) ? acc[(size_t)n0 * 768 + idx] : 0.0f;
    }
    __syncthreads();

    if (t < 256) {
        float a[16];
#pragma unroll
        for (int i = 0; i < 16; ++i) a[i] = 0.0f;
        for (int u = 0; u < 192; ++u) {
            float w = Wo_s[u * 256 + t];
#pragma unroll
            for (int i = 0; i < 16; ++i) a[i] += sAcc[i * 768 + u] * w;
        }
        float b = bo_s[t];
#pragma unroll
        for (int i = 0; i < 16; ++i) {
            int n = n0 + i;
            if (n < nNodes) out[(size_t)n * 640 + t] = a[i] * INV_S192 + b;
        }
    }

    {
        int o = t & 127, c = t >> 7;
        float a[16];
#pragma unroll
        for (int i = 0; i < 16; ++i) a[i] = 0.0f;
        for (int u = 0; u < 192; ++u) {
            float w = Wo_v[u * 128 + o];
#pragma unroll
            for (int i = 0; i < 16; ++i) a[i] += sAcc[i * 768 + 192 + u * 3 + c] * w;
        }
#pragma unroll
        for (int i = 0; i < 16; ++i) {
            int n = n0 + i;
            if (n < nNodes) out[(size_t)n * 640 + 256 + o * 3 + c] = a[i] * INV_S192;
        }
    }
}

// ---------------- launcher ----------------
extern "C" void kernel_launch(void* const* d_in, const int* in_sizes, int n_in,
                              void* d_out, int out_size, void* d_ws, size_t ws_size,
                              hipStream_t stream)
{
    const float* x      = (const float*)d_in[0];
    const int*   ei     = (const int*)d_in[1];     // int32 from harness
    const float* ea     = (const float*)d_in[2];
    const float* esh    = (const float*)d_in[3];
    const float* Wpre_s = (const float*)d_in[4];
    const float* bpre_s = (const float*)d_in[5];
    const float* Wpre_v = (const float*)d_in[6];
    const float* Wg1    = (const float*)d_in[7];
    const float* bg1    = (const float*)d_in[8];
    const float* Wg2    = (const float*)d_in[9];
    const float* bg2    = (const float*)d_in[10];
    const float* Wn_s   = (const float*)d_in[11];
    const float* bn_s   = (const float*)d_in[12];
    const float* Wn_v   = (const float*)d_in[13];
    const float* Wf1    = (const float*)d_in[14];
    const float* Wf2    = (const float*)d_in[15];
    const float* Wl1    = (const float*)d_in[16];
    const float* Wl2    = (const float*)d_in[17];
    const float* Wo_s   = (const float*)d_in[18];
    const float* bo_s   = (const float*)d_in[19];
    const float* Wo_v   = (const float*)d_in[20];

    const int nNodes = in_sizes[0] / 320;
    const int nEdges = in_sizes[2] / 32;

    float* ws = (float*)d_ws;
    size_t off = 0;
    float* preV = ws + off; off += (size_t)nNodes * 192;
    float* qv   = ws + off; off += (size_t)nNodes * 32;
    float* xs3  = ws + off; off += (size_t)nNodes * 128;
    float* xv3  = ws + off; off += (size_t)nNodes * 192;
    float* Wl1p = ws + off; off += 128 * 32;
    float* accb = ws + off; off += (size_t)nNodes * 768;
    int* ibase    = (int*)(ws + off);
    int* deg      = ibase;
    int* cursor   = ibase + nNodes;
    int* rowStart = ibase + 2 * nNodes;            // nNodes+1 entries
    int* perm     = ibase + 3 * nNodes + 1;        // nEdges entries

    // ---- counting sort of edges by dst ----
    k_zeroi<<<256, 256, 0, stream>>>(deg, 2 * nNodes);   // deg + cursor
    k_hist<<<512, 256, 0, stream>>>(ei, deg, nEdges);
    k_scan<<<1, 1024, 0, stream>>>(deg, rowStart, nNodes);
    k_perm<<<512, 256, 0, stream>>>(ei, rowStart, cursor, perm, nEdges);

    k_prep<<<(128 * 32 + 255) / 256, 256, 0, stream>>>(Wl1, Wl1p);

    int nodeBlocks = (nNodes + 15) / 16;
    k_node<<<nodeBlocks, 192, 0, stream>>>(
        x, Wpre_s, bpre_s, Wpre_v, Wg1, bg1, Wg2, bg2,
        Wn_s, bn_s, Wn_v, Wl1p, preV, qv, xs3, xv3, nNodes);

    k_edge2<<<nNodes, 384, 0, stream>>>(
        ei, ea, esh, Wf1, Wf2, Wl1, Wl2, preV, qv, xs3, xv3,
        rowStart, perm, accb, nEdges);

    k_out<<<nodeBlocks, 384, 0, stream>>>(accb, Wo_s, bo_s, Wo_v, (float*)d_out, nNodes);
}

// Round 8
// 1954.717 us; speedup vs baseline: 1.0682x; 1.0682x over previous
//
#include <hip/hip_runtime.h>
#include <math.h>

// ---------------- constants ----------------
#define MS 128
#define MV 64
#define RBF 32
#define HID 32
#define TPW 384
#define EB 8
#define NPB 16            // nodes per edge-block

__device__ __forceinline__ float sspf(float x) {
    float r = (x > 0.0f) ? (x + log1pf(expf(-x))) : log1pf(expf(x));
    return r - 0.6931471805599453f;
}
__device__ __forceinline__ float siluf(float x) { return x / (1.0f + expf(-x)); }

__constant__ float INV_S128 = 0.08838834764831845f;
__constant__ float INV_S64  = 0.125f;
__constant__ float INV_S320 = 0.05590169943749474f;
__constant__ float INV_S32  = 0.17677669529663687f;
__constant__ float INV_S192 = 0.07216878364870323f;
#define C1F 0.8660254037844386f
#define INV_S3F 0.5773502691896258f

// ---------------- sort pipeline ----------------
__global__ void k_zeroi(int* __restrict__ p, int n) {
    int i = blockIdx.x * blockDim.x + threadIdx.x;
    int stride = gridDim.x * blockDim.x;
    for (; i < n; i += stride) p[i] = 0;
}

__global__ void k_hist(const int* __restrict__ ei, int* __restrict__ deg, int nEdges) {
    int e = blockIdx.x * blockDim.x + threadIdx.x;
    int stride = gridDim.x * blockDim.x;
    for (; e < nEdges; e += stride) atomicAdd(&deg[ei[e]], 1);
}

__global__ __launch_bounds__(1024) void k_scan(const int* __restrict__ deg,
                                               int* __restrict__ rowStart, int n) {
    __shared__ int s[1024];
    const int t = threadIdx.x;
    const int CH = (n + 1023) >> 10;
    const int beg = t * CH, end = min(beg + CH, n);
    int sum = 0;
    for (int i = beg; i < end; ++i) sum += deg[i];
    s[t] = sum;
    __syncthreads();
    for (int off = 1; off < 1024; off <<= 1) {
        int v = (t >= off) ? s[t - off] : 0;
        __syncthreads();
        s[t] += v;
        __syncthreads();
    }
    int run = s[t] - sum;
    for (int i = beg; i < end; ++i) { rowStart[i] = run; run += deg[i]; }
    if (t == 1023) rowStart[n] = s[1023];
}

__global__ void k_perm(const int* __restrict__ ei, const int* __restrict__ rowStart,
                       int* __restrict__ cursor, int* __restrict__ perm, int nEdges) {
    int e = blockIdx.x * blockDim.x + threadIdx.x;
    int stride = gridDim.x * blockDim.x;
    for (; e < nEdges; e += stride) {
        int d = ei[e];
        int pos = rowStart[d] + atomicAdd(&cursor[d], 1);
        perm[pos] = e;
    }
}

// gather edge data into dst-sorted order (sequential streams for k_edge3)
__global__ void k_gather(const int* __restrict__ ei, const int* __restrict__ perm,
                         const float* __restrict__ ea, const float* __restrict__ esh,
                         int* __restrict__ srcP, float* __restrict__ eaP,
                         float* __restrict__ eshP, int nEdges) {
    int tid = blockIdx.x * blockDim.x + threadIdx.x;
    int i = tid >> 5, o = tid & 31;
    if (i >= nEdges) return;
    int ed = perm[i];
    eaP[(size_t)i * 32 + o] = ea[(size_t)ed * 32 + o];
    if (o < 4) eshP[(size_t)i * 4 + o] = esh[(size_t)ed * 4 + o];
    if (o == 4) srcP[i] = ei[nEdges + ed];
}

// ---------------- K0: fold Wl1 rows 0..127 + 128..255 ----------------
__global__ void k_prep(const float* __restrict__ Wl1, float* __restrict__ Wl1p) {
    int i = blockIdx.x * blockDim.x + threadIdx.x;
    if (i < 128 * 32) Wl1p[i] = Wl1[i] + Wl1[128 * 32 + i];
}

// ---------------- K1: node kernel (SoA writes for preV / xv3) ----------------
__global__ __launch_bounds__(192) void k_node(
    const float* __restrict__ x,
    const float* __restrict__ Wpre_s, const float* __restrict__ bpre_s,
    const float* __restrict__ Wpre_v,
    const float* __restrict__ Wg1, const float* __restrict__ bg1,
    const float* __restrict__ Wg2, const float* __restrict__ bg2,
    const float* __restrict__ Wn_s, const float* __restrict__ bn_s,
    const float* __restrict__ Wn_v,
    const float* __restrict__ Wl1p,
    float* __restrict__ preVc, float* __restrict__ qv,
    float* __restrict__ xs3, float* __restrict__ xv3c,
    int nNodes)
{
    __shared__ float sF0[16 * 192];
    __shared__ float sXV[16 * 192];
    __shared__ float sA[16 * 192];
    __shared__ float sB[16 * 192];

    const int t = threadIdx.x;
    const int n0 = blockIdx.x * 16;
    const size_t N64 = (size_t)nNodes * 64;

    for (int idx = t; idx < 16 * 320; idx += 192) {
        int i = idx / 320, j = idx - i * 320;
        int n = n0 + i;
        float v = (n < nNodes) ? x[(size_t)n * 320 + j] : 0.0f;
        if (j < 128) sF0[i * 192 + j] = v;
        else         sXV[i * 192 + (j - 128)] = v;
    }
    __syncthreads();

    for (int task = t; task < 16 * 64; task += 192) {
        int i = task >> 6, u = task & 63;
        float a = sXV[i * 192 + u * 3];
        float b = sXV[i * 192 + u * 3 + 1];
        float c = sXV[i * 192 + u * 3 + 2];
        sF0[i * 192 + 128 + u] = sqrtf(a * a + b * b + c * c + 1e-12f);
    }

    {   // pre_v -> planar preVc
        int c = t >> 6, o = t & 63;
        float acc[16];
#pragma unroll
        for (int i = 0; i < 16; ++i) acc[i] = 0.0f;
        for (int u = 0; u < 64; ++u) {
            float w = Wpre_v[u * 64 + o];
#pragma unroll
            for (int i = 0; i < 16; ++i) acc[i] += sXV[i * 192 + u * 3 + c] * w;
        }
#pragma unroll
        for (int i = 0; i < 16; ++i) {
            int n = n0 + i;
            if (n < nNodes) preVc[(size_t)c * N64 + (size_t)n * 64 + o] = acc[i] * INV_S64;
        }
    }
    __syncthreads();

    if (t < 128) {
        float acc[16];
#pragma unroll
        for (int i = 0; i < 16; ++i) acc[i] = 0.0f;
        for (int u = 0; u < 128; ++u) {
            float w = Wpre_s[u * 128 + t];
#pragma unroll
            for (int i = 0; i < 16; ++i) acc[i] += sF0[i * 192 + u] * w;
        }
        float b = bpre_s[t];
#pragma unroll
        for (int i = 0; i < 16; ++i) sA[i * 192 + t] = acc[i] * INV_S128 + b;
    }
    __syncthreads();

    for (int task = t; task < 16 * 32; task += 192) {
        int i = task >> 5, o = task & 31;
        float a = 0.0f;
        for (int u = 0; u < 128; ++u) a += sA[i * 192 + u] * Wl1p[u * 32 + o];
        int n = n0 + i;
        if (n < nNodes) qv[(size_t)n * 32 + o] = a;
    }
    __syncthreads();

    {
        float acc[16];
#pragma unroll
        for (int i = 0; i < 16; ++i) acc[i] = 0.0f;
        for (int u = 0; u < 192; ++u) {
            float w = Wg1[u * 192 + t];
#pragma unroll
            for (int i = 0; i < 16; ++i) acc[i] += sF0[i * 192 + u] * w;
        }
        float b = bg1[t];
        __syncthreads();
#pragma unroll
        for (int i = 0; i < 16; ++i) sA[i * 192 + t] = siluf(acc[i] + b);
    }
    __syncthreads();

    {
        float acc[16];
#pragma unroll
        for (int i = 0; i < 16; ++i) acc[i] = 0.0f;
        for (int u = 0; u < 192; ++u) {
            float w = Wg2[u * 192 + t];
#pragma unroll
            for (int i = 0; i < 16; ++i) acc[i] += sA[i * 192 + u] * w;
        }
        float b = bg2[t];
#pragma unroll
        for (int i = 0; i < 16; ++i) sB[i * 192 + t] = acc[i] + b;
    }
    __syncthreads();

    if (t < 128) {
        float acc[16];
#pragma unroll
        for (int i = 0; i < 16; ++i) acc[i] = 0.0f;
        for (int u = 0; u < 128; ++u) {
            float w = Wn_s[u * 128 + t];
#pragma unroll
            for (int i = 0; i < 16; ++i) acc[i] += sB[i * 192 + u] * w;
        }
        float b = bn_s[t];
#pragma unroll
        for (int i = 0; i < 16; ++i) {
            int n = n0 + i;
            if (n < nNodes) xs3[(size_t)n * 128 + t] = acc[i] * INV_S128 + b;
        }
    }

    {
        int u = t / 3;
#pragma unroll
        for (int i = 0; i < 16; ++i) {
            sF0[i * 192 + t] = sXV[i * 192 + t] * sB[i * 192 + 128 + u];
        }
    }
    __syncthreads();

    {   // xv3 -> planar xv3c
        int c = t >> 6, o = t & 63;
        float acc[16];
#pragma unroll
        for (int i = 0; i < 16; ++i) acc[i] = 0.0f;
        for (int u = 0; u < 64; ++u) {
            float w = Wn_v[u * 64 + o];
#pragma unroll
            for (int i = 0; i < 16; ++i) acc[i] += sF0[i * 192 + u * 3 + c] * w;
        }
#pragma unroll
        for (int i = 0; i < 16; ++i) {
            int n = n0 + i;
            if (n < nNodes) xv3c[(size_t)c * N64 + (size_t)n * 64 + o] = acc[i] * INV_S64;
        }
    }
}

// ---------------- K2: multi-node dst-sorted edge kernel ----------------
// useGather=1: eaP/eshP/srcP are dst-sorted sequential streams (fast path).
// useGather=0: index original ea/esh/ei through perm (ws-constrained fallback).
__global__ __launch_bounds__(384) void k_edge3(
    const float* __restrict__ eaP, const float* __restrict__ eshP,
    const int* __restrict__ srcP,
    const float* __restrict__ ea, const float* __restrict__ esh,
    const int* __restrict__ ei, const int* __restrict__ perm,
    const float* __restrict__ Wf1, const float* __restrict__ Wf2,
    const float* __restrict__ Wl1, const float* __restrict__ Wl2,
    const float* __restrict__ preVc, const float* __restrict__ qv,
    const float* __restrict__ xs3, const float* __restrict__ xv3c,
    const int* __restrict__ rowStart,
    float* __restrict__ acc,
    int nNodes, int nEdges, int useGather)
{
    __shared__ float sWf1T[32][36];   // [o][u], padded row
    __shared__ float sWl1T[32][68];   // [o][u], padded row
    __shared__ float sQ[32];
    __shared__ float sPd[3][64];
    __shared__ float sEA[EB][32];
    __shared__ float sSH[EB][4];
    __shared__ float sIp1[EB][64];
    __shared__ float sH[EB][64];      // [0..31]=hA, [32..63]=hB
    __shared__ float sW[EB][384];
    __shared__ int   sSrc[EB];

    const int t = threadIdx.x;
    const size_t N64 = (size_t)nNodes * 64;

    // persistent per-thread weight columns (64 VGPRs)
    float rWf2[32], rWl2[32];
#pragma unroll
    for (int u = 0; u < 32; ++u) {
        rWf2[u] = Wf2[u * 384 + t];
        rWl2[u] = Wl2[u * 384 + t];
    }
    // transposed weight tiles
    for (int i = t; i < 32 * 32; i += 384) { int u = i >> 5, o = i & 31; sWf1T[o][u] = Wf1[i]; }
    for (int i = t; i < 64 * 32; i += 384) { int u = i >> 5, o = i & 31; sWl1T[o][u] = Wl1[256 * 32 + i]; }

    const int nBeg = blockIdx.x * NPB;
    const int nEnd = min(nBeg + NPB, nNodes);

    for (int n = nBeg; n < nEnd; ++n) {
        // per-node staging (group-top barrier orders these vs readers)
        if (t < 32) sQ[t] = qv[(size_t)n * 32 + t];
        else if (t >= 64 && t < 256) {
            int k = t - 64;
            sPd[k >> 6][k & 63] = preVc[(size_t)(k >> 6) * N64 + (size_t)n * 64 + (k & 63)];
        }
        float a0 = 0.0f, a1 = 0.0f;
        const int e_beg = rowStart[n];
        const int e_end = rowStart[n + 1];

        for (int base = e_beg; base < e_end; base += EB) {
            const int rem = min(EB, e_end - base);
            __syncthreads();   // staging/sQ/sPd/sW hazards

            // ---- phase A: stage edge data + ip1 ----
            if (t < 256) {
                int e = t >> 5, o = t & 31;
                float v = 0.0f;
                if (e < rem) {
                    if (useGather) v = eaP[(size_t)(base + e) * 32 + o];
                    else           v = ea[(size_t)perm[base + e] * 32 + o];
                }
                sEA[e][o] = v;
            } else if (t < 288) {
                int k = t - 256, e = k >> 2, c = k & 3;
                float v = 0.0f;
                if (e < rem) {
                    if (useGather) v = eshP[(size_t)(base + e) * 4 + c];
                    else           v = esh[(size_t)perm[base + e] * 4 + c];
                }
                sSH[e][c] = v;
            } else if (t < 296) {
                int e = t - 288;
                int s = n;
                if (e < rem) {
                    if (useGather) s = srcP[base + e];
                    else           s = ei[nEdges + perm[base + e]];
                }
                sSrc[e] = s;
            }
            for (int task = t; task < EB * 64; task += 384) {
                int e = task >> 6, u = task & 63;
                int s = n;
                if (e < rem) {
                    if (useGather) s = srcP[base + e];
                    else           s = ei[nEdges + perm[base + e]];
                }
                float v = preVc[(size_t)s * 64 + u]             * sPd[0][u]
                        + preVc[N64 + (size_t)s * 64 + u]       * sPd[1][u]
                        + preVc[2 * N64 + (size_t)s * 64 + u]   * sPd[2][u];
                sIp1[e][u] = v * (1.0f / 3.0f);
            }
            __syncthreads();

            // ---- phase B: hA / hB (float4 LDS, bank-rotated) ----
            if (t < 256) {
                int e = t >> 5, o = t & 31;
                float a = sQ[o];
                const float4* ip = (const float4*)(&sIp1[e][0]);
                const float4* wl = (const float4*)(&sWl1T[o][0]);
#pragma unroll
                for (int k = 0; k < 16; ++k) {
                    int kk = (k + o) & 15;
                    float4 va = ip[kk], vb = wl[kk];
                    a += va.x * vb.x + va.y * vb.y + va.z * vb.z + va.w * vb.w;
                }
                sH[e][32 + o] = sspf(a * INV_S320);
            } else {
#pragma unroll
                for (int k2 = 0; k2 < 2; ++k2) {
                    int task = (t - 256) + 128 * k2;
                    int e = task >> 5, o = task & 31;
                    float a = 0.0f;
                    const float4* eav = (const float4*)(&sEA[e][0]);
                    const float4* wf  = (const float4*)(&sWf1T[o][0]);
#pragma unroll
                    for (int k = 0; k < 8; ++k) {
                        int kk = (k + o) & 7;
                        float4 va = eav[kk], vb = wf[kk];
                        a += va.x * vb.x + va.y * vb.y + va.z * vb.z + va.w * vb.w;
                    }
                    sH[e][o] = sspf(a * INV_S32);
                }
            }
            __syncthreads();

            // ---- phase C: w = (hA@Wf2) * (hB@Wl2) / 32 (float4 broadcast + reg weights) ----
#pragma unroll
            for (int e = 0; e < EB; ++e) {
                const float4* h4 = (const float4*)(&sH[e][0]);
                float a = 0.0f, b = 0.0f;
#pragma unroll
                for (int k = 0; k < 8; ++k) {
                    float4 ha = h4[k];
                    a += ha.x * rWf2[4 * k] + ha.y * rWf2[4 * k + 1]
                       + ha.z * rWf2[4 * k + 2] + ha.w * rWf2[4 * k + 3];
                }
#pragma unroll
                for (int k = 0; k < 8; ++k) {
                    float4 hb = h4[8 + k];
                    b += hb.x * rWl2[4 * k] + hb.y * rWl2[4 * k + 1]
                       + hb.z * rWl2[4 * k + 2] + hb.w * rWl2[4 * k + 3];
                }
                sW[e][t] = a * b * (1.0f / 32.0f);
            }
            __syncthreads();

            // ---- phase D: tensor products -> register accumulators ----
#pragma unroll
            for (int e = 0; e < EB; ++e) {
                int s = sSrc[e];
                float sh0  = sSH[e][0];
                float sh1x = sSH[e][1], sh1y = sSH[e][2], sh1z = sSH[e][3];
                if (t < 128) {
                    float hs = xs3[(size_t)s * 128 + t];
                    a0 += 0.5f * sW[e][t] * hs * sh0;                 // out0a
                    a1 += C1F * sW[e][128 + t] * hs * sh1y;           // out1a c=1
                } else if (t < 192) {
                    int j = t - 128;
                    float v0 = xv3c[(size_t)s * 64 + j];
                    float v1 = xv3c[N64 + (size_t)s * 64 + j];
                    float v2 = xv3c[2 * N64 + (size_t)s * 64 + j];
                    float dot = v0 * sh1x + v1 * sh1y + v2 * sh1z;
                    a0 += 0.5f * sW[e][320 + j] * dot * INV_S3F;      // out0b
                    a1 += C1F * sW[e][256 + j] * v1 * sh0;            // out1b c=1
                } else if (t < 320) {
                    int m = t - 192;
                    float w2h = C1F * sW[e][128 + m] * xs3[(size_t)s * 128 + m];
                    a0 += w2h * sh1x;                                 // out1a c=0
                    a1 += w2h * sh1z;                                 // out1a c=2
                } else {
                    int j = t - 320;
                    float v0 = xv3c[(size_t)s * 64 + j];
                    float v2 = xv3c[2 * N64 + (size_t)s * 64 + j];
                    float wj = C1F * sW[e][256 + j] * sh0;
                    a0 += wj * v0;                                    // out1b c=0
                    a1 += wj * v2;                                    // out1b c=2
                }
            }
        }

        // planar acc row: [es(192) | ev_c0(192) | ev_c1(192) | ev_c2(192)]
        acc[(size_t)n * 768 + t]       = a0;
        acc[(size_t)n * 768 + 384 + t] = a1;
    }
}

// ---------------- K3: output kernel (planar acc) ----------------
__global__ __launch_bounds__(384) void k_out(
    const float* __restrict__ acc,
    const float* __restrict__ Wo_s, const float* __restrict__ bo_s,
    const float* __restrict__ Wo_v,
    float* __restrict__ out, int nNodes)
{
    __shared__ float sAcc[16 * 768];
    const int t = threadIdx.x;
    const int n0 = blockIdx.x * 16;

    for (int idx = t; idx < 16 * 768; idx += 384) {
        int i = idx / 768;
        int n = n0 + i;
        sAcc[idx] = (n < nNodes) ? acc[(size_t)n0 * 768 + idx] : 0.0f;
    }
    __syncthreads();

    if (t < 256) {
        float a[16];
#pragma unroll
        for (int i = 0; i < 16; ++i) a[i] = 0.0f;
        for (int u = 0; u < 192; ++u) {
            float w = Wo_s[u * 256 + t];
#pragma unroll
            for (int i = 0; i < 16; ++i) a[i] += sAcc[i * 768 + u] * w;
        }
        float b = bo_s[t];
#pragma unroll
        for (int i = 0; i < 16; ++i) {
            int n = n0 + i;
            if (n < nNodes) out[(size_t)n * 640 + t] = a[i] * INV_S192 + b;
        }
    }

    {
        int o = t & 127, c = t >> 7;
        float a[16];
#pragma unroll
        for (int i = 0; i < 16; ++i) a[i] = 0.0f;
        for (int u = 0; u < 192; ++u) {
            float w = Wo_v[u * 128 + o];
#pragma unroll
            for (int i = 0; i < 16; ++i) a[i] += sAcc[i * 768 + 192 + c * 192 + u] * w;
        }
#pragma unroll
        for (int i = 0; i < 16; ++i) {
            int n = n0 + i;
            if (n < nNodes) out[(size_t)n * 640 + 256 + o * 3 + c] = a[i] * INV_S192;
        }
    }
}

// ---------------- launcher ----------------
extern "C" void kernel_launch(void* const* d_in, const int* in_sizes, int n_in,
                              void* d_out, int out_size, void* d_ws, size_t ws_size,
                              hipStream_t stream)
{
    const float* x      = (const float*)d_in[0];
    const int*   ei     = (const int*)d_in[1];
    const float* ea     = (const float*)d_in[2];
    const float* esh    = (const float*)d_in[3];
    const float* Wpre_s = (const float*)d_in[4];
    const float* bpre_s = (const float*)d_in[5];
    const float* Wpre_v = (const float*)d_in[6];
    const float* Wg1    = (const float*)d_in[7];
    const float* bg1    = (const float*)d_in[8];
    const float* Wg2    = (const float*)d_in[9];
    const float* bg2    = (const float*)d_in[10];
    const float* Wn_s   = (const float*)d_in[11];
    const float* bn_s   = (const float*)d_in[12];
    const float* Wn_v   = (const float*)d_in[13];
    const float* Wf1    = (const float*)d_in[14];
    const float* Wf2    = (const float*)d_in[15];
    const float* Wl1    = (const float*)d_in[16];
    const float* Wl2    = (const float*)d_in[17];
    const float* Wo_s   = (const float*)d_in[18];
    const float* bo_s   = (const float*)d_in[19];
    const float* Wo_v   = (const float*)d_in[20];

    const int nNodes = in_sizes[0] / 320;
    const int nEdges = in_sizes[2] / 32;

    // base layout (always present)
    float* ws = (float*)d_ws;
    size_t off = 0;
    float* preVc = ws + off; off += (size_t)nNodes * 192;
    float* qv    = ws + off; off += (size_t)nNodes * 32;
    float* xs3   = ws + off; off += (size_t)nNodes * 128;
    float* xv3c  = ws + off; off += (size_t)nNodes * 192;
    float* Wl1p  = ws + off; off += 128 * 32;
    float* accb  = ws + off; off += (size_t)nNodes * 768;

    // optional gathered streams
    const size_t gatherElems = (size_t)nEdges * 32 + (size_t)nEdges * 4;   // eaP + eshP (floats)
    const size_t baseIntElems = 3 * (size_t)nNodes + 1 + (size_t)nEdges;   // deg+cursor+rowStart+perm
    const size_t needGather = (off + gatherElems) * 4
                            + (baseIntElems + (size_t)nEdges) * 4;         // + srcP
    const int useGather = (ws_size >= needGather) ? 1 : 0;

    float* eaP = nullptr; float* eshP = nullptr; int* srcP = nullptr;
    if (useGather) {
        eaP  = ws + off; off += (size_t)nEdges * 32;
        eshP = ws + off; off += (size_t)nEdges * 4;
    }
    int* ibase    = (int*)(ws + off);
    int* deg      = ibase;
    int* cursor   = ibase + nNodes;
    int* rowStart = ibase + 2 * nNodes;       // nNodes+1
    int* perm     = ibase + 3 * nNodes + 1;   // nEdges
    if (useGather) srcP = perm + nEdges;      // nEdges

    // counting sort by dst (+ optional gather into sorted order)
    k_zeroi<<<256, 256, 0, stream>>>(deg, 2 * nNodes);
    k_hist<<<512, 256, 0, stream>>>(ei, deg, nEdges);
    k_scan<<<1, 1024, 0, stream>>>(deg, rowStart, nNodes);
    k_perm<<<512, 256, 0, stream>>>(ei, rowStart, cursor, perm, nEdges);
    if (useGather) {
        k_gather<<<(nEdges * 32 + 255) / 256, 256, 0, stream>>>(
            ei, perm, ea, esh, srcP, eaP, eshP, nEdges);
    }

    k_prep<<<(128 * 32 + 255) / 256, 256, 0, stream>>>(Wl1, Wl1p);

    int nodeBlocks = (nNodes + 15) / 16;
    k_node<<<nodeBlocks, 192, 0, stream>>>(
        x, Wpre_s, bpre_s, Wpre_v, Wg1, bg1, Wg2, bg2,
        Wn_s, bn_s, Wn_v, Wl1p, preVc, qv, xs3, xv3c, nNodes);

    k_edge3<<<(nNodes + NPB - 1) / NPB, 384, 0, stream>>>(
        eaP, eshP, srcP, ea, esh, ei, perm,
        Wf1, Wf2, Wl1, Wl2, preVc, qv, xs3, xv3c,
        rowStart, accb, nNodes, nEdges, useGather);

    k_out<<<nodeBlocks, 384, 0, stream>>>(accb, Wo_s, bo_s, Wo_v, (float*)d_out, nNodes);
}

// Round 9
// 1433.032 us; speedup vs baseline: 1.4571x; 1.3640x over previous
//
#include <hip/hip_runtime.h>
#include <math.h>

// ---------------- constants ----------------
#define MS 128
#define MV 64
#define RBF 32
#define HID 32
#define TPW 384
#define EB 8
#define NPB 4             // nodes per edge-block (k_edge4)

__device__ __forceinline__ float sspf(float x) {
    float r = (x > 0.0f) ? (x + log1pf(expf(-x))) : log1pf(expf(x));
    return r - 0.6931471805599453f;
}
__device__ __forceinline__ float siluf(float x) { return x / (1.0f + expf(-x)); }

__constant__ float INV_S128 = 0.08838834764831845f;
__constant__ float INV_S64  = 0.125f;
__constant__ float INV_S320 = 0.05590169943749474f;
__constant__ float INV_S32  = 0.17677669529663687f;
__constant__ float INV_S192 = 0.07216878364870323f;
#define C1F 0.8660254037844386f
#define INV_S3F 0.5773502691896258f

// ---------------- sort pipeline ----------------
__global__ void k_zeroi(int* __restrict__ p, int n) {
    int i = blockIdx.x * blockDim.x + threadIdx.x;
    int stride = gridDim.x * blockDim.x;
    for (; i < n; i += stride) p[i] = 0;
}

__global__ void k_hist(const int* __restrict__ ei, int* __restrict__ deg, int nEdges) {
    int e = blockIdx.x * blockDim.x + threadIdx.x;
    int stride = gridDim.x * blockDim.x;
    for (; e < nEdges; e += stride) atomicAdd(&deg[ei[e]], 1);
}

__global__ __launch_bounds__(1024) void k_scan(const int* __restrict__ deg,
                                               int* __restrict__ rowStart, int n) {
    __shared__ int s[1024];
    const int t = threadIdx.x;
    const int CH = (n + 1023) >> 10;
    const int beg = t * CH, end = min(beg + CH, n);
    int sum = 0;
    for (int i = beg; i < end; ++i) sum += deg[i];
    s[t] = sum;
    __syncthreads();
    for (int off = 1; off < 1024; off <<= 1) {
        int v = (t >= off) ? s[t - off] : 0;
        __syncthreads();
        s[t] += v;
        __syncthreads();
    }
    int run = s[t] - sum;
    for (int i = beg; i < end; ++i) { rowStart[i] = run; run += deg[i]; }
    if (t == 1023) rowStart[n] = s[1023];
}

__global__ void k_perm(const int* __restrict__ ei, const int* __restrict__ rowStart,
                       int* __restrict__ cursor, int* __restrict__ perm,
                       int* __restrict__ dstP, int nEdges) {
    int e = blockIdx.x * blockDim.x + threadIdx.x;
    int stride = gridDim.x * blockDim.x;
    for (; e < nEdges; e += stride) {
        int d = ei[e];
        int pos = rowStart[d] + atomicAdd(&cursor[d], 1);
        perm[pos] = e;
        dstP[pos] = d;
    }
}

__global__ void k_src(const int* __restrict__ ei, const int* __restrict__ perm,
                      int* __restrict__ srcP, int nEdges) {
    int i = blockIdx.x * blockDim.x + threadIdx.x;
    if (i < nEdges) srcP[i] = ei[nEdges + perm[i]];
}

// ---------------- K0: fold Wl1 rows 0..127 + 128..255 ----------------
__global__ void k_prep(const float* __restrict__ Wl1, float* __restrict__ Wl1p) {
    int i = blockIdx.x * blockDim.x + threadIdx.x;
    if (i < 128 * 32) Wl1p[i] = Wl1[i] + Wl1[128 * 32 + i];
}

// ---------------- K1: node kernel (unchanged; SoA preVc/xv3c) ----------------
__global__ __launch_bounds__(192) void k_node(
    const float* __restrict__ x,
    const float* __restrict__ Wpre_s, const float* __restrict__ bpre_s,
    const float* __restrict__ Wpre_v,
    const float* __restrict__ Wg1, const float* __restrict__ bg1,
    const float* __restrict__ Wg2, const float* __restrict__ bg2,
    const float* __restrict__ Wn_s, const float* __restrict__ bn_s,
    const float* __restrict__ Wn_v,
    const float* __restrict__ Wl1p,
    float* __restrict__ preVc, float* __restrict__ qv,
    float* __restrict__ xs3, float* __restrict__ xv3c,
    int nNodes)
{
    __shared__ float sF0[16 * 192];
    __shared__ float sXV[16 * 192];
    __shared__ float sA[16 * 192];
    __shared__ float sB[16 * 192];

    const int t = threadIdx.x;
    const int n0 = blockIdx.x * 16;
    const size_t N64 = (size_t)nNodes * 64;

    for (int idx = t; idx < 16 * 320; idx += 192) {
        int i = idx / 320, j = idx - i * 320;
        int n = n0 + i;
        float v = (n < nNodes) ? x[(size_t)n * 320 + j] : 0.0f;
        if (j < 128) sF0[i * 192 + j] = v;
        else         sXV[i * 192 + (j - 128)] = v;
    }
    __syncthreads();

    for (int task = t; task < 16 * 64; task += 192) {
        int i = task >> 6, u = task & 63;
        float a = sXV[i * 192 + u * 3];
        float b = sXV[i * 192 + u * 3 + 1];
        float c = sXV[i * 192 + u * 3 + 2];
        sF0[i * 192 + 128 + u] = sqrtf(a * a + b * b + c * c + 1e-12f);
    }

    {   // pre_v -> planar preVc
        int c = t >> 6, o = t & 63;
        float acc[16];
#pragma unroll
        for (int i = 0; i < 16; ++i) acc[i] = 0.0f;
        for (int u = 0; u < 64; ++u) {
            float w = Wpre_v[u * 64 + o];
#pragma unroll
            for (int i = 0; i < 16; ++i) acc[i] += sXV[i * 192 + u * 3 + c] * w;
        }
#pragma unroll
        for (int i = 0; i < 16; ++i) {
            int n = n0 + i;
            if (n < nNodes) preVc[(size_t)c * N64 + (size_t)n * 64 + o] = acc[i] * INV_S64;
        }
    }
    __syncthreads();

    if (t < 128) {
        float acc[16];
#pragma unroll
        for (int i = 0; i < 16; ++i) acc[i] = 0.0f;
        for (int u = 0; u < 128; ++u) {
            float w = Wpre_s[u * 128 + t];
#pragma unroll
            for (int i = 0; i < 16; ++i) acc[i] += sF0[i * 192 + u] * w;
        }
        float b = bpre_s[t];
#pragma unroll
        for (int i = 0; i < 16; ++i) sA[i * 192 + t] = acc[i] * INV_S128 + b;
    }
    __syncthreads();

    for (int task = t; task < 16 * 32; task += 192) {
        int i = task >> 5, o = task & 31;
        float a = 0.0f;
        for (int u = 0; u < 128; ++u) a += sA[i * 192 + u] * Wl1p[u * 32 + o];
        int n = n0 + i;
        if (n < nNodes) qv[(size_t)n * 32 + o] = a;
    }
    __syncthreads();

    {
        float acc[16];
#pragma unroll
        for (int i = 0; i < 16; ++i) acc[i] = 0.0f;
        for (int u = 0; u < 192; ++u) {
            float w = Wg1[u * 192 + t];
#pragma unroll
            for (int i = 0; i < 16; ++i) acc[i] += sF0[i * 192 + u] * w;
        }
        float b = bg1[t];
        __syncthreads();
#pragma unroll
        for (int i = 0; i < 16; ++i) sA[i * 192 + t] = siluf(acc[i] + b);
    }
    __syncthreads();

    {
        float acc[16];
#pragma unroll
        for (int i = 0; i < 16; ++i) acc[i] = 0.0f;
        for (int u = 0; u < 192; ++u) {
            float w = Wg2[u * 192 + t];
#pragma unroll
            for (int i = 0; i < 16; ++i) acc[i] += sA[i * 192 + u] * w;
        }
        float b = bg2[t];
#pragma unroll
        for (int i = 0; i < 16; ++i) sB[i * 192 + t] = acc[i] + b;
    }
    __syncthreads();

    if (t < 128) {
        float acc[16];
#pragma unroll
        for (int i = 0; i < 16; ++i) acc[i] = 0.0f;
        for (int u = 0; u < 128; ++u) {
            float w = Wn_s[u * 128 + t];
#pragma unroll
            for (int i = 0; i < 16; ++i) acc[i] += sB[i * 192 + u] * w;
        }
        float b = bn_s[t];
#pragma unroll
        for (int i = 0; i < 16; ++i) {
            int n = n0 + i;
            if (n < nNodes) xs3[(size_t)n * 128 + t] = acc[i] * INV_S128 + b;
        }
    }

    {
        int u = t / 3;
#pragma unroll
        for (int i = 0; i < 16; ++i) {
            sF0[i * 192 + t] = sXV[i * 192 + t] * sB[i * 192 + 128 + u];
        }
    }
    __syncthreads();

    {   // xv3 -> planar xv3c
        int c = t >> 6, o = t & 63;
        float acc[16];
#pragma unroll
        for (int i = 0; i < 16; ++i) acc[i] = 0.0f;
        for (int u = 0; u < 64; ++u) {
            float w = Wn_v[u * 64 + o];
#pragma unroll
            for (int i = 0; i < 16; ++i) acc[i] += sF0[i * 192 + u * 3 + c] * w;
        }
#pragma unroll
        for (int i = 0; i < 16; ++i) {
            int n = n0 + i;
            if (n < nNodes) xv3c[(size_t)c * N64 + (size_t)n * 64 + o] = acc[i] * INV_S64;
        }
    }
}

// ---------------- K2a: per-edge h kernel (one barrier, 8 edges/block) ----------------
__global__ __launch_bounds__(256) void k_h(
    const int* __restrict__ perm, const int* __restrict__ srcP,
    const int* __restrict__ dstP,
    const float* __restrict__ ea,
    const float* __restrict__ Wf1, const float* __restrict__ Wl1,
    const float* __restrict__ preVc, const float* __restrict__ qv,
    float* __restrict__ hbuf, int nNodes, int nEdges)
{
    __shared__ float sWf1T[32][36];   // [o][u], padded
    __shared__ float sWl1T[32][68];   // [o][u], padded
    __shared__ float sEA[EB][32];
    __shared__ float sIp1[EB][64];
    __shared__ float sQd[EB][32];

    const int t = threadIdx.x;
    const int e0 = blockIdx.x * EB;
    const size_t N64 = (size_t)nNodes * 64;

    // weight tiles (transposed)
    for (int i = t; i < 32 * 32; i += 256) { int u = i >> 5, o = i & 31; sWf1T[o][u] = Wf1[i]; }
    for (int i = t; i < 64 * 32; i += 256) { int u = i >> 5, o = i & 31; sWl1T[o][u] = Wl1[256 * 32 + i]; }

    // stage ip1 (gathers; massively parallel across 32000 blocks)
    for (int task = t; task < EB * 64; task += 256) {
        int e = task >> 6, u = task & 63;
        int ee = e0 + e;
        float v = 0.0f;
        if (ee < nEdges) {
            int s = srcP[ee], d = dstP[ee];
            v = preVc[(size_t)d * 64 + u]           * preVc[(size_t)s * 64 + u]
              + preVc[N64 + (size_t)d * 64 + u]     * preVc[N64 + (size_t)s * 64 + u]
              + preVc[2 * N64 + (size_t)d * 64 + u] * preVc[2 * N64 + (size_t)s * 64 + u];
        }
        sIp1[e][u] = v * (1.0f / 3.0f);
    }
    // stage ea row + q[dst]
    {
        int e = t >> 5, o = t & 31;
        int ee = e0 + e;
        sEA[e][o] = (ee < nEdges) ? ea[(size_t)perm[ee] * 32 + o] : 0.0f;
        sQd[e][o] = (ee < nEdges) ? qv[(size_t)dstP[ee] * 32 + o] : 0.0f;
    }
    __syncthreads();

    // compute: thread -> (e, o)
    {
        int e = t >> 5, o = t & 31;
        int ee = e0 + e;

        float a = 0.0f;
        const float4* eav = (const float4*)(&sEA[e][0]);
        const float4* wf  = (const float4*)(&sWf1T[o][0]);
#pragma unroll
        for (int k = 0; k < 8; ++k) {
            int kk = (k + o) & 7;
            float4 va = eav[kk], vb = wf[kk];
            a += va.x * vb.x + va.y * vb.y + va.z * vb.z + va.w * vb.w;
        }

        float b = sQd[e][o];
        const float4* ip = (const float4*)(&sIp1[e][0]);
        const float4* wl = (const float4*)(&sWl1T[o][0]);
#pragma unroll
        for (int k = 0; k < 16; ++k) {
            int kk = (k + o) & 15;
            float4 va = ip[kk], vb = wl[kk];
            b += va.x * vb.x + va.y * vb.y + va.z * vb.z + va.w * vb.w;
        }

        if (ee < nEdges) {
            hbuf[(size_t)ee * 64 + o]      = sspf(a * INV_S32);
            hbuf[(size_t)ee * 64 + 32 + o] = sspf(b * INV_S320);
        }
    }
}

// ---------------- K2b: dst-sorted edge kernel, h via uniform s_load ----------------
__global__ __launch_bounds__(384) void k_edge4(
    const float* __restrict__ hbuf,
    const float* __restrict__ esh,
    const int* __restrict__ perm, const int* __restrict__ srcP,
    const float* __restrict__ Wf2, const float* __restrict__ Wl2,
    const float* __restrict__ xs3, const float* __restrict__ xv3c,
    const int* __restrict__ rowStart,
    float* __restrict__ acc, int nNodes)
{
    __shared__ float sW[EB][384];
    __shared__ float sSH[EB][4];
    __shared__ int   sSrc[EB];

    const int t = threadIdx.x;
    const size_t N64 = (size_t)nNodes * 64;

    float rWf2[32], rWl2[32];
#pragma unroll
    for (int u = 0; u < 32; ++u) {
        rWf2[u] = Wf2[u * 384 + t];
        rWl2[u] = Wl2[u * 384 + t];
    }

    const int nBeg = blockIdx.x * NPB;
    const int nEnd = min(nBeg + NPB, nNodes);

    for (int n = nBeg; n < nEnd; ++n) {
        float a0 = 0.0f, a1 = 0.0f;
        const int e_beg = rowStart[n];
        const int e_end = rowStart[n + 1];

        for (int base = e_beg; base < e_end; base += EB) {
            const int rem = min(EB, e_end - base);
            __syncthreads();   // protect sW/sSH/sSrc from previous iteration

            // tiny stage (no barrier needed before phase C; C doesn't read these)
            if (t < 32) {
                int e = t >> 2, c = t & 3;
                sSH[e][c] = (e < rem) ? esh[(size_t)perm[base + e] * 4 + c] : 0.0f;
            } else if (t < 40) {
                int e = t - 32;
                sSrc[e] = (e < rem) ? srcP[base + e] : n;
            }

            // phase C: w = (hA@Wf2)*(hB@Wl2)/32 ; h rows wave-uniform -> s_load
            for (int e = 0; e < EB; ++e) {
                int eg = __builtin_amdgcn_readfirstlane(base + e);
                const float* h = hbuf + (size_t)eg * 64;
                float a = 0.0f, b = 0.0f;
#pragma unroll
                for (int u = 0; u < 32; ++u) a += h[u] * rWf2[u];
#pragma unroll
                for (int u = 0; u < 32; ++u) b += h[32 + u] * rWl2[u];
                sW[e][t] = (e < rem) ? a * b * (1.0f / 32.0f) : 0.0f;
            }
            __syncthreads();

            // phase D: tensor products -> register accumulators
#pragma unroll
            for (int e = 0; e < EB; ++e) {
                int s = sSrc[e];
                float sh0  = sSH[e][0];
                float sh1x = sSH[e][1], sh1y = sSH[e][2], sh1z = sSH[e][3];
                if (t < 128) {
                    float hs = xs3[(size_t)s * 128 + t];
                    a0 += 0.5f * sW[e][t] * hs * sh0;                 // out0a
                    a1 += C1F * sW[e][128 + t] * hs * sh1y;           // out1a c=1
                } else if (t < 192) {
                    int j = t - 128;
                    float v0 = xv3c[(size_t)s * 64 + j];
                    float v1 = xv3c[N64 + (size_t)s * 64 + j];
                    float v2 = xv3c[2 * N64 + (size_t)s * 64 + j];
                    float dot = v0 * sh1x + v1 * sh1y + v2 * sh1z;
                    a0 += 0.5f * sW[e][320 + j] * dot * INV_S3F;      // out0b
                    a1 += C1F * sW[e][256 + j] * v1 * sh0;            // out1b c=1
                } else if (t < 320) {
                    int m = t - 192;
                    float w2h = C1F * sW[e][128 + m] * xs3[(size_t)s * 128 + m];
                    a0 += w2h * sh1x;                                 // out1a c=0
                    a1 += w2h * sh1z;                                 // out1a c=2
                } else {
                    int j = t - 320;
                    float v0 = xv3c[(size_t)s * 64 + j];
                    float v2 = xv3c[2 * N64 + (size_t)s * 64 + j];
                    float wj = C1F * sW[e][256 + j] * sh0;
                    a0 += wj * v0;                                    // out1b c=0
                    a1 += wj * v2;                                    // out1b c=2
                }
            }
        }

        acc[(size_t)n * 768 + t]       = a0;
        acc[(size_t)n * 768 + 384 + t] = a1;
    }
}

// ---------------- fallback edge kernel (round-8 proven, perm-direct) ----------------
__global__ __launch_bounds__(384) void k_edge3(
    const float* __restrict__ ea, const float* __restrict__ esh,
    const int* __restrict__ ei, const int* __restrict__ perm,
    const float* __restrict__ Wf1, const float* __restrict__ Wf2,
    const float* __restrict__ Wl1, const float* __restrict__ Wl2,
    const float* __restrict__ preVc, const float* __restrict__ qv,
    const float* __restrict__ xs3, const float* __restrict__ xv3c,
    const int* __restrict__ rowStart,
    float* __restrict__ acc,
    int nNodes, int nEdges)
{
    __shared__ float sWf1T[32][36];
    __shared__ float sWl1T[32][68];
    __shared__ float sQ[32];
    __shared__ float sPd[3][64];
    __shared__ float sEA[EB][32];
    __shared__ float sSH[EB][4];
    __shared__ float sIp1[EB][64];
    __shared__ float sH[EB][64];
    __shared__ float sW[EB][384];
    __shared__ int   sSrc[EB];

    const int t = threadIdx.x;
    const size_t N64 = (size_t)nNodes * 64;

    float rWf2[32], rWl2[32];
#pragma unroll
    for (int u = 0; u < 32; ++u) {
        rWf2[u] = Wf2[u * 384 + t];
        rWl2[u] = Wl2[u * 384 + t];
    }
    for (int i = t; i < 32 * 32; i += 384) { int u = i >> 5, o = i & 31; sWf1T[o][u] = Wf1[i]; }
    for (int i = t; i < 64 * 32; i += 384) { int u = i >> 5, o = i & 31; sWl1T[o][u] = Wl1[256 * 32 + i]; }

    const int nBeg = blockIdx.x * 16;
    const int nEnd = min(nBeg + 16, nNodes);

    for (int n = nBeg; n < nEnd; ++n) {
        if (t < 32) sQ[t] = qv[(size_t)n * 32 + t];
        else if (t >= 64 && t < 256) {
            int k = t - 64;
            sPd[k >> 6][k & 63] = preVc[(size_t)(k >> 6) * N64 + (size_t)n * 64 + (k & 63)];
        }
        float a0 = 0.0f, a1 = 0.0f;
        const int e_beg = rowStart[n];
        const int e_end = rowStart[n + 1];

        for (int base = e_beg; base < e_end; base += EB) {
            const int rem = min(EB, e_end - base);
            __syncthreads();

            if (t < 256) {
                int e = t >> 5, o = t & 31;
                sEA[e][o] = (e < rem) ? ea[(size_t)perm[base + e] * 32 + o] : 0.0f;
            } else if (t < 288) {
                int k = t - 256, e = k >> 2, c = k & 3;
                sSH[e][c] = (e < rem) ? esh[(size_t)perm[base + e] * 4 + c] : 0.0f;
            } else if (t < 296) {
                int e = t - 288;
                sSrc[e] = (e < rem) ? ei[nEdges + perm[base + e]] : n;
            }
            for (int task = t; task < EB * 64; task += 384) {
                int e = task >> 6, u = task & 63;
                int s = (e < rem) ? ei[nEdges + perm[base + e]] : n;
                float v = preVc[(size_t)s * 64 + u]           * sPd[0][u]
                        + preVc[N64 + (size_t)s * 64 + u]     * sPd[1][u]
                        + preVc[2 * N64 + (size_t)s * 64 + u] * sPd[2][u];
                sIp1[e][u] = v * (1.0f / 3.0f);
            }
            __syncthreads();

            if (t < 256) {
                int e = t >> 5, o = t & 31;
                float a = sQ[o];
                const float4* ip = (const float4*)(&sIp1[e][0]);
                const float4* wl = (const float4*)(&sWl1T[o][0]);
#pragma unroll
                for (int k = 0; k < 16; ++k) {
                    int kk = (k + o) & 15;
                    float4 va = ip[kk], vb = wl[kk];
                    a += va.x * vb.x + va.y * vb.y + va.z * vb.z + va.w * vb.w;
                }
                sH[e][32 + o] = sspf(a * INV_S320);
            } else {
#pragma unroll
                for (int k2 = 0; k2 < 2; ++k2) {
                    int task = (t - 256) + 128 * k2;
                    int e = task >> 5, o = task & 31;
                    float a = 0.0f;
                    const float4* eav = (const float4*)(&sEA[e][0]);
                    const float4* wf  = (const float4*)(&sWf1T[o][0]);
#pragma unroll
                    for (int k = 0; k < 8; ++k) {
                        int kk = (k + o) & 7;
                        float4 va = eav[kk], vb = wf[kk];
                        a += va.x * vb.x + va.y * vb.y + va.z * vb.z + va.w * vb.w;
                    }
                    sH[e][o] = sspf(a * INV_S32);
                }
            }
            __syncthreads();

#pragma unroll
            for (int e = 0; e < EB; ++e) {
                const float4* h4 = (const float4*)(&sH[e][0]);
                float a = 0.0f, b = 0.0f;
#pragma unroll
                for (int k = 0; k < 8; ++k) {
                    float4 ha = h4[k];
                    a += ha.x * rWf2[4 * k] + ha.y * rWf2[4 * k + 1]
                       + ha.z * rWf2[4 * k + 2] + ha.w * rWf2[4 * k + 3];
                }
#pragma unroll
                for (int k = 0; k < 8; ++k) {
                    float4 hb = h4[8 + k];
                    b += hb.x * rWl2[4 * k] + hb.y * rWl2[4 * k + 1]
                       + hb.z * rWl2[4 * k + 2] + hb.w * rWl2[4 * k + 3];
                }
                sW[e][t] = a * b * (1.0f / 32.0f);
            }
            __syncthreads();

#pragma unroll
            for (int e = 0; e < EB; ++e) {
                int s = sSrc[e];
                float sh0  = sSH[e][0];
                float sh1x = sSH[e][1], sh1y = sSH[e][2], sh1z = sSH[e][3];
                if (t < 128) {
                    float hs = xs3[(size_t)s * 128 + t];
                    a0 += 0.5f * sW[e][t] * hs * sh0;
                    a1 += C1F * sW[e][128 + t] * hs * sh1y;
                } else if (t < 192) {
                    int j = t - 128;
                    float v0 = xv3c[(size_t)s * 64 + j];
                    float v1 = xv3c[N64 + (size_t)s * 64 + j];
                    float v2 = xv3c[2 * N64 + (size_t)s * 64 + j];
                    float dot = v0 * sh1x + v1 * sh1y + v2 * sh1z;
                    a0 += 0.5f * sW[e][320 + j] * dot * INV_S3F;
                    a1 += C1F * sW[e][256 + j] * v1 * sh0;
                } else if (t < 320) {
                    int m = t - 192;
                    float w2h = C1F * sW[e][128 + m] * xs3[(size_t)s * 128 + m];
                    a0 += w2h * sh1x;
                    a1 += w2h * sh1z;
                } else {
                    int j = t - 320;
                    float v0 = xv3c[(size_t)s * 64 + j];
                    float v2 = xv3c[2 * N64 + (size_t)s * 64 + j];
                    float wj = C1F * sW[e][256 + j] * sh0;
                    a0 += wj * v0;
                    a1 += wj * v2;
                }
            }
        }

        acc[(size_t)n * 768 + t]       = a0;
        acc[(size_t)n * 768 + 384 + t] = a1;
    }
}

// ---------------- K3: output kernel (planar acc) ----------------
__global__ __launch_bounds__(384) void k_out(
    const float* __restrict__ acc,
    const float* __restrict__ Wo_s, const float* __restrict__ bo_s,
    const float* __restrict__ Wo_v,
    float* __restrict__ out, int nNodes)
{
    __shared__ float sAcc[16 * 768];
    const int t = threadIdx.x;
    const int n0 = blockIdx.x * 16;

    for (int idx = t; idx < 16 * 768; idx += 384) {
        int i = idx / 768;
        int n = n0 + i;
        sAcc[idx] = (n < nNodes) ? acc[(size_t)n0 * 768 + idx] : 0.0f;
    }
    __syncthreads();

    if (t < 256) {
        float a[16];
#pragma unroll
        for (int i = 0; i < 16; ++i) a[i] = 0.0f;
        for (int u = 0; u < 192; ++u) {
            float w = Wo_s[u * 256 + t];
#pragma unroll
            for (int i = 0; i < 16; ++i) a[i] += sAcc[i * 768 + u] * w;
        }
        float b = bo_s[t];
#pragma unroll
        for (int i = 0; i < 16; ++i) {
            int n = n0 + i;
            if (n < nNodes) out[(size_t)n * 640 + t] = a[i] * INV_S192 + b;
        }
    }

    {
        int o = t & 127, c = t >> 7;
        float a[16];
#pragma unroll
        for (int i = 0; i < 16; ++i) a[i] = 0.0f;
        for (int u = 0; u < 192; ++u) {
            float w = Wo_v[u * 128 + o];
#pragma unroll
            for (int i = 0; i < 16; ++i) a[i] += sAcc[i * 768 + 192 + c * 192 + u] * w;
        }
#pragma unroll
        for (int i = 0; i < 16; ++i) {
            int n = n0 + i;
            if (n < nNodes) out[(size_t)n * 640 + 256 + o * 3 + c] = a[i] * INV_S192;
        }
    }
}

// ---------------- launcher ----------------
extern "C" void kernel_launch(void* const* d_in, const int* in_sizes, int n_in,
                              void* d_out, int out_size, void* d_ws, size_t ws_size,
                              hipStream_t stream)
{
    const float* x      = (const float*)d_in[0];
    const int*   ei     = (const int*)d_in[1];
    const float* ea     = (const float*)d_in[2];
    const float* esh    = (const float*)d_in[3];
    const float* Wpre_s = (const float*)d_in[4];
    const float* bpre_s = (const float*)d_in[5];
    const float* Wpre_v = (const float*)d_in[6];
    const float* Wg1    = (const float*)d_in[7];
    const float* bg1    = (const float*)d_in[8];
    const float* Wg2    = (const float*)d_in[9];
    const float* bg2    = (const float*)d_in[10];
    const float* Wn_s   = (const float*)d_in[11];
    const float* bn_s   = (const float*)d_in[12];
    const float* Wn_v   = (const float*)d_in[13];
    const float* Wf1    = (const float*)d_in[14];
    const float* Wf2    = (const float*)d_in[15];
    const float* Wl1    = (const float*)d_in[16];
    const float* Wl2    = (const float*)d_in[17];
    const float* Wo_s   = (const float*)d_in[18];
    const float* bo_s   = (const float*)d_in[19];
    const float* Wo_v   = (const float*)d_in[20];

    const int nNodes = in_sizes[0] / 320;
    const int nEdges = in_sizes[2] / 32;

    float* ws = (float*)d_ws;
    size_t off = 0;
    float* preVc = ws + off; off += (size_t)nNodes * 192;
    float* qv    = ws + off; off += (size_t)nNodes * 32;
    float* xs3   = ws + off; off += (size_t)nNodes * 128;
    float* xv3c  = ws + off; off += (size_t)nNodes * 192;
    float* Wl1p  = ws + off; off += 128 * 32;
    float* accb  = ws + off; off += (size_t)nNodes * 768;

    // full path needs hbuf (E rows of 64 + 8 rows slack)
    const size_t hbufElems = (size_t)nEdges * 64 + 8 * 64;
    const size_t intElems  = 3 * (size_t)nNodes + 1 + 3 * (size_t)nEdges;
    const size_t needFull  = (off + hbufElems) * 4 + intElems * 4;
    const int useFull = (ws_size >= needFull) ? 1 : 0;

    float* hbuf = nullptr;
    if (useFull) { hbuf = ws + off; off += hbufElems; }

    int* ibase    = (int*)(ws + off);
    int* deg      = ibase;
    int* cursor   = ibase + nNodes;
    int* rowStart = ibase + 2 * nNodes;       // nNodes+1
    int* perm     = ibase + 3 * nNodes + 1;   // nEdges
    int* srcP     = perm + nEdges;            // nEdges
    int* dstP     = srcP + nEdges;            // nEdges

    // counting sort by dst
    k_zeroi<<<256, 256, 0, stream>>>(deg, 2 * nNodes);
    k_hist<<<512, 256, 0, stream>>>(ei, deg, nEdges);
    k_scan<<<1, 1024, 0, stream>>>(deg, rowStart, nNodes);
    k_perm<<<512, 256, 0, stream>>>(ei, rowStart, cursor, perm, dstP, nEdges);
    k_src<<<(nEdges + 255) / 256, 256, 0, stream>>>(ei, perm, srcP, nEdges);

    k_prep<<<(128 * 32 + 255) / 256, 256, 0, stream>>>(Wl1, Wl1p);

    int nodeBlocks = (nNodes + 15) / 16;
    k_node<<<nodeBlocks, 192, 0, stream>>>(
        x, Wpre_s, bpre_s, Wpre_v, Wg1, bg1, Wg2, bg2,
        Wn_s, bn_s, Wn_v, Wl1p, preVc, qv, xs3, xv3c, nNodes);

    if (useFull) {
        k_h<<<(nEdges + EB - 1) / EB, 256, 0, stream>>>(
            perm, srcP, dstP, ea, Wf1, Wl1, preVc, qv, hbuf, nNodes, nEdges);
        k_edge4<<<(nNodes + NPB - 1) / NPB, 384, 0, stream>>>(
            hbuf, esh, perm, srcP, Wf2, Wl2, xs3, xv3c, rowStart, accb, nNodes);
    } else {
        k_edge3<<<(nNodes + 15) / 16, 384, 0, stream>>>(
            ea, esh, ei, perm, Wf1, Wf2, Wl1, Wl2,
            preVc, qv, xs3, xv3c, rowStart, accb, nNodes, nEdges);
    }

    k_out<<<nodeBlocks, 384, 0, stream>>>(accb, Wo_s, bo_s, Wo_v, (float*)d_out, nNodes);
}